// Round 6
// baseline (31.797 us; speedup 1.0000x reference)
//
#include <hip/hip_runtime.h>

#define BB 8
#define NN 256
#define DD 128
#define LN_EPS 1e-5f

// ---------------------------------------------------------------------------
// k_proj: hi = x@w1[:D], hjb = x@w1[D:] + b1, xw3 = x@w3[:D] + b3
// grid 256 blocks (8 rows) x 512 threads: 2 cols/thread (dp2), 8-way k-split.
// x staged in LDS (broadcast b128, amortized over 3 outputs x 2 cols),
// weights via coalesced float2 VMEM. Partials combined through LDS.
// ---------------------------------------------------------------------------
__global__ __launch_bounds__(512) void k_proj(const float* __restrict__ x,
                                              const float* __restrict__ w1,
                                              const float* __restrict__ b1,
                                              const float* __restrict__ w3,
                                              const float* __restrict__ b3,
                                              float* __restrict__ hi,
                                              float* __restrict__ hjb,
                                              float* __restrict__ xw3) {
    __shared__ float xs[8 * DD];       // 4 KB
    __shared__ float part[8 * 1024];   // 32 KB
    const int row0 = blockIdx.x * 8;
    const int tid  = threadIdx.x;
    #pragma unroll
    for (int t = 0; t < 2; ++t) {
        int idx = tid + t * 512;
        xs[idx] = x[row0 * DD + idx];
    }
    __syncthreads();

    const int dp2 = (tid & 63) * 2;    // cols dp2, dp2+1
    const int kg  = tid >> 6;          // 0..7 (wave)
    const int kb  = kg * 16;

    float2 acc_a[8], acc_b[8], acc_c[8];
    #pragma unroll
    for (int r = 0; r < 8; ++r) {
        acc_a[r] = make_float2(0.f, 0.f);
        acc_b[r] = make_float2(0.f, 0.f);
        acc_c[r] = make_float2(0.f, 0.f);
    }

    #pragma unroll
    for (int q4 = 0; q4 < 4; ++q4) {
        const int k0 = kb + q4 * 4;
        float2 wa[4], wb[4], wc[4];
        #pragma unroll
        for (int q = 0; q < 4; ++q) {
            wa[q] = *(const float2*)&w1[(k0 + q) * DD + dp2];
            wb[q] = *(const float2*)&w1[(DD + k0 + q) * DD + dp2];
            wc[q] = *(const float2*)&w3[(k0 + q) * DD + dp2];
        }
        #pragma unroll
        for (int r = 0; r < 8; ++r) {
            const float4 xv = *(const float4*)&xs[r * DD + k0];  // LDS broadcast
            const float xq[4] = {xv.x, xv.y, xv.z, xv.w};
            #pragma unroll
            for (int q = 0; q < 4; ++q) {
                acc_a[r].x = fmaf(xq[q], wa[q].x, acc_a[r].x);
                acc_a[r].y = fmaf(xq[q], wa[q].y, acc_a[r].y);
                acc_b[r].x = fmaf(xq[q], wb[q].x, acc_b[r].x);
                acc_b[r].y = fmaf(xq[q], wb[q].y, acc_b[r].y);
                acc_c[r].x = fmaf(xq[q], wc[q].x, acc_c[r].x);
                acc_c[r].y = fmaf(xq[q], wc[q].y, acc_c[r].y);
            }
        }
    }

    // round A -> hi
    #pragma unroll
    for (int r = 0; r < 8; ++r) *(float2*)&part[kg * 1024 + r * DD + dp2] = acc_a[r];
    __syncthreads();
    #pragma unroll
    for (int m = 0; m < 2; ++m) {
        int idx = tid + m * 512; int r = idx >> 7, d = idx & 127;
        float s = 0.f;
        #pragma unroll
        for (int w = 0; w < 8; ++w) s += part[w * 1024 + r * DD + d];
        hi[(row0 + r) * DD + d] = s;
    }
    __syncthreads();
    // round B -> hjb (+b1)
    #pragma unroll
    for (int r = 0; r < 8; ++r) *(float2*)&part[kg * 1024 + r * DD + dp2] = acc_b[r];
    __syncthreads();
    #pragma unroll
    for (int m = 0; m < 2; ++m) {
        int idx = tid + m * 512; int r = idx >> 7, d = idx & 127;
        float s = 0.f;
        #pragma unroll
        for (int w = 0; w < 8; ++w) s += part[w * 1024 + r * DD + d];
        hjb[(row0 + r) * DD + d] = s + b1[d];
    }
    __syncthreads();
    // round C -> xw3 (+b3)
    #pragma unroll
    for (int r = 0; r < 8; ++r) *(float2*)&part[kg * 1024 + r * DD + dp2] = acc_c[r];
    __syncthreads();
    #pragma unroll
    for (int m = 0; m < 2; ++m) {
        int idx = tid + m * 512; int r = idx >> 7, d = idx & 127;
        float s = 0.f;
        #pragma unroll
        for (int w = 0; w < 8; ++w) s += part[w * 1024 + r * DD + d];
        xw3[(row0 + r) * DD + d] = s + b3[d];
    }
}

// ---------------------------------------------------------------------------
// k_fused: pair accumulation (s, asum in LDS; hjb streamed from L2) + whole
// tail. 256 blocks (8 rows) x 512 threads.
// smem (floats): [0,8192) part | [8192,11264) a_tt[256][12] (later u1s@8192,
// resS@9216) | [11264,12288) ssp | [12288,13312) aggs | [13312..) asum
// ---------------------------------------------------------------------------
__global__ __launch_bounds__(512) void k_fused(const float* __restrict__ adj,
                                               const float* __restrict__ x,
                                               const float* __restrict__ hi,
                                               const float* __restrict__ hjb,
                                               const float* __restrict__ xw3,
                                               const float* __restrict__ w2,
                                               const float* __restrict__ b2,
                                               const float* __restrict__ w3,
                                               const float* __restrict__ w4,
                                               const float* __restrict__ b4,
                                               const float* __restrict__ g,
                                               const float* __restrict__ bet,
                                               float* __restrict__ out) {
    __shared__ float smem[13352];
    float* const part     = smem;            // [8][8][128]
    float* const a_tt     = smem + 8192;     // [256][12] (rows 0..7 used)
    float* const u1s      = smem + 8192;     // [8][128] alias (a_tt dead)
    float* const resS     = smem + 9216;     // [8][128] alias
    float* const ssp      = smem + 11264;    // [8][128]
    float* const aggs     = smem + 12288;    // [8][128]
    float* const asum_sub = smem + 13312;    // [8][4]
    float* const asum_s   = smem + 13344;    // [8]

    const int bid = blockIdx.x;
    const int b   = bid >> 5;
    const int i0  = (bid & 31) * 8;
    const int tid = threadIdx.x;

    // ---- stage transposed masked adjacency + asum partials via shfl
    #pragma unroll
    for (int t = 0; t < 4; ++t) {
        int idx = tid + t * 512;            // 0..2047
        int il = idx >> 8, j = idx & 255;   // il wave-uniform
        int ig = i0 + il;
        float av = adj[((size_t)b * NN + ig) * NN + j];
        av = (j == ig) ? 0.f : av;
        a_tt[j * 12 + il] = av;
        float s = av;
        #pragma unroll
        for (int m = 32; m; m >>= 1) s += __shfl_xor(s, m);
        if ((tid & 63) == 0) asum_sub[il * 4 + ((tid & 255) >> 6)] = s;
    }
    __syncthreads();

    // ---- pair: 4 rows x 4 d per thread, 8-way j-split, hjb from global
    {
        const int dq = tid & 31;
        const int rh = (tid >> 5) & 1;
        const int js = tid >> 6;            // wave = j-split
        const int r0 = rh * 4;
        const float* hib = hi + ((size_t)b * NN + i0 + r0) * DD + dq * 4;
        const float4 hi0 = *(const float4*)(hib);
        const float4 hi1 = *(const float4*)(hib + DD);
        const float4 hi2 = *(const float4*)(hib + 2 * DD);
        const float4 hi3 = *(const float4*)(hib + 3 * DD);
        float4 ac0 = {0,0,0,0}, ac1 = {0,0,0,0}, ac2 = {0,0,0,0}, ac3 = {0,0,0,0};
        const float* hp = hjb + ((size_t)b * NN + js * 32) * DD + dq * 4;
        const float* ap = a_tt + (js * 32) * 12 + r0;
        #pragma unroll 4
        for (int jj = 0; jj < 32; ++jj) {
            const float4 hv = *(const float4*)(hp + jj * DD);
            const float4 a4 = *(const float4*)(ap + jj * 12);   // 4 rows' a
            ac0.x = fmaf(fmaxf(hi0.x + hv.x, 0.f), a4.x, ac0.x);
            ac0.y = fmaf(fmaxf(hi0.y + hv.y, 0.f), a4.x, ac0.y);
            ac0.z = fmaf(fmaxf(hi0.z + hv.z, 0.f), a4.x, ac0.z);
            ac0.w = fmaf(fmaxf(hi0.w + hv.w, 0.f), a4.x, ac0.w);
            ac1.x = fmaf(fmaxf(hi1.x + hv.x, 0.f), a4.y, ac1.x);
            ac1.y = fmaf(fmaxf(hi1.y + hv.y, 0.f), a4.y, ac1.y);
            ac1.z = fmaf(fmaxf(hi1.z + hv.z, 0.f), a4.y, ac1.z);
            ac1.w = fmaf(fmaxf(hi1.w + hv.w, 0.f), a4.y, ac1.w);
            ac2.x = fmaf(fmaxf(hi2.x + hv.x, 0.f), a4.z, ac2.x);
            ac2.y = fmaf(fmaxf(hi2.y + hv.y, 0.f), a4.z, ac2.y);
            ac2.z = fmaf(fmaxf(hi2.z + hv.z, 0.f), a4.z, ac2.z);
            ac2.w = fmaf(fmaxf(hi2.w + hv.w, 0.f), a4.z, ac2.w);
            ac3.x = fmaf(fmaxf(hi3.x + hv.x, 0.f), a4.w, ac3.x);
            ac3.y = fmaf(fmaxf(hi3.y + hv.y, 0.f), a4.w, ac3.y);
            ac3.z = fmaf(fmaxf(hi3.z + hv.z, 0.f), a4.w, ac3.z);
            ac3.w = fmaf(fmaxf(hi3.w + hv.w, 0.f), a4.w, ac3.w);
        }
        float* pp = part + js * 1024 + r0 * DD + dq * 4;
        *(float4*)(pp)          = ac0;
        *(float4*)(pp + DD)     = ac1;
        *(float4*)(pp + 2 * DD) = ac2;
        *(float4*)(pp + 3 * DD) = ac3;
    }
    __syncthreads();

    // ---- combine j-splits -> ssp; finalize asum
    if (tid < 8)
        asum_s[tid] = asum_sub[tid * 4] + asum_sub[tid * 4 + 1]
                    + asum_sub[tid * 4 + 2] + asum_sub[tid * 4 + 3];
    #pragma unroll
    for (int m = 0; m < 2; ++m) {
        int idx = tid + m * 512;
        float s = 0.f;
        #pragma unroll
        for (int w = 0; w < 8; ++w) s += part[w * 1024 + idx];
        ssp[idx] = s;
    }
    __syncthreads();

    const int dp = tid & 63;            // cols dp, dp+64
    const int kg = tid >> 6;            // wave
    const int kb = kg * 16;

    // ---- stage A: agg = ssp @ w2
    {
        float wv0[16], wv1[16];
        #pragma unroll
        for (int k = 0; k < 16; ++k) {
            wv0[k] = w2[(kb + k) * DD + dp];
            wv1[k] = w2[(kb + k) * DD + dp + 64];
        }
        #pragma unroll
        for (int r = 0; r < 8; ++r) {
            float a0 = 0.f, a1 = 0.f;
            #pragma unroll
            for (int q = 0; q < 4; ++q) {
                const float4 sv = *(const float4*)&ssp[r * DD + kb + q * 4];
                a0 = fmaf(sv.x, wv0[q*4+0], a0); a1 = fmaf(sv.x, wv1[q*4+0], a1);
                a0 = fmaf(sv.y, wv0[q*4+1], a0); a1 = fmaf(sv.y, wv1[q*4+1], a1);
                a0 = fmaf(sv.z, wv0[q*4+2], a0); a1 = fmaf(sv.z, wv1[q*4+2], a1);
                a0 = fmaf(sv.w, wv0[q*4+3], a0); a1 = fmaf(sv.w, wv1[q*4+3], a1);
            }
            part[kg * 1024 + r * DD + dp]      = a0;
            part[kg * 1024 + r * DD + dp + 64] = a1;
        }
    }
    __syncthreads();
    #pragma unroll
    for (int m = 0; m < 2; ++m) {
        int idx = tid + m * 512; int r = idx >> 7, d = idx & 127;
        float s = 0.f;
        #pragma unroll
        for (int w = 0; w < 8; ++w) s += part[w * 1024 + idx];
        aggs[idx] = s + b2[d] * asum_s[r];
    }
    __syncthreads();

    // ---- stage B: u1 = relu(xw3 + agg @ w3b)
    {
        const float* w3b = w3 + DD * DD;
        float wv0[16], wv1[16];
        #pragma unroll
        for (int k = 0; k < 16; ++k) {
            wv0[k] = w3b[(kb + k) * DD + dp];
            wv1[k] = w3b[(kb + k) * DD + dp + 64];
        }
        #pragma unroll
        for (int r = 0; r < 8; ++r) {
            float a0 = 0.f, a1 = 0.f;
            #pragma unroll
            for (int q = 0; q < 4; ++q) {
                const float4 av = *(const float4*)&aggs[r * DD + kb + q * 4];
                a0 = fmaf(av.x, wv0[q*4+0], a0); a1 = fmaf(av.x, wv1[q*4+0], a1);
                a0 = fmaf(av.y, wv0[q*4+1], a0); a1 = fmaf(av.y, wv1[q*4+1], a1);
                a0 = fmaf(av.z, wv0[q*4+2], a0); a1 = fmaf(av.z, wv1[q*4+2], a1);
                a0 = fmaf(av.w, wv0[q*4+3], a0); a1 = fmaf(av.w, wv1[q*4+3], a1);
            }
            part[kg * 1024 + r * DD + dp]      = a0;
            part[kg * 1024 + r * DD + dp + 64] = a1;
        }
    }
    __syncthreads();
    #pragma unroll
    for (int m = 0; m < 2; ++m) {
        int idx = tid + m * 512;
        float s = xw3[((size_t)b * NN + i0) * DD + idx];
        #pragma unroll
        for (int w = 0; w < 8; ++w) s += part[w * 1024 + idx];
        u1s[idx] = fmaxf(s, 0.f);
    }
    __syncthreads();

    // ---- stage C: res = x + u1 @ w4 + b4
    {
        float wv0[16], wv1[16];
        #pragma unroll
        for (int k = 0; k < 16; ++k) {
            wv0[k] = w4[(kb + k) * DD + dp];
            wv1[k] = w4[(kb + k) * DD + dp + 64];
        }
        #pragma unroll
        for (int r = 0; r < 8; ++r) {
            float a0 = 0.f, a1 = 0.f;
            #pragma unroll
            for (int q = 0; q < 4; ++q) {
                const float4 uv = *(const float4*)&u1s[r * DD + kb + q * 4];
                a0 = fmaf(uv.x, wv0[q*4+0], a0); a1 = fmaf(uv.x, wv1[q*4+0], a1);
                a0 = fmaf(uv.y, wv0[q*4+1], a0); a1 = fmaf(uv.y, wv1[q*4+1], a1);
                a0 = fmaf(uv.z, wv0[q*4+2], a0); a1 = fmaf(uv.z, wv1[q*4+2], a1);
                a0 = fmaf(uv.w, wv0[q*4+3], a0); a1 = fmaf(uv.w, wv1[q*4+3], a1);
            }
            part[kg * 1024 + r * DD + dp]      = a0;
            part[kg * 1024 + r * DD + dp + 64] = a1;
        }
    }
    __syncthreads();
    #pragma unroll
    for (int m = 0; m < 2; ++m) {
        int idx = tid + m * 512; int d = idx & 127;
        float s = x[((size_t)b * NN + i0) * DD + idx] + b4[d];
        #pragma unroll
        for (int w = 0; w < 8; ++w) s += part[w * 1024 + idx];
        resS[idx] = s;
    }
    __syncthreads();

    // ---- LayerNorm: one wave per row
    {
        const int r = tid >> 6, l = tid & 63;
        const float2 v = *(const float2*)&resS[r * DD + l * 2];
        float s1 = v.x + v.y;
        float s2 = v.x * v.x + v.y * v.y;
        #pragma unroll
        for (int m = 32; m; m >>= 1) {
            s1 += __shfl_xor(s1, m);
            s2 += __shfl_xor(s2, m);
        }
        const float mu = s1 * (1.f / DD);
        const float rs = rsqrtf(s2 * (1.f / DD) - mu * mu + LN_EPS);
        const int d = l * 2;
        const float2 gv = *(const float2*)&g[d];
        const float2 bv = *(const float2*)&bet[d];
        float2 o;
        o.x = (v.x - mu) * rs * gv.x + bv.x;
        o.y = (v.y - mu) * rs * gv.y + bv.y;
        *(float2*)&out[((size_t)b * NN + i0 + r) * DD + d] = o;
    }
}

extern "C" void kernel_launch(void* const* d_in, const int* in_sizes, int n_in,
                              void* d_out, int out_size, void* d_ws, size_t ws_size,
                              hipStream_t stream) {
    (void)in_sizes; (void)n_in; (void)out_size; (void)ws_size;
    const float* x      = (const float*)d_in[0];
    const float* adj    = (const float*)d_in[1];
    const float* msg_w1 = (const float*)d_in[2];
    const float* msg_b1 = (const float*)d_in[3];
    const float* msg_w2 = (const float*)d_in[4];
    const float* msg_b2 = (const float*)d_in[5];
    const float* upd_w1 = (const float*)d_in[6];
    const float* upd_b1 = (const float*)d_in[7];
    const float* upd_w2 = (const float*)d_in[8];
    const float* upd_b2 = (const float*)d_in[9];
    const float* ln_g   = (const float*)d_in[10];
    const float* ln_b   = (const float*)d_in[11];
    float* out = (float*)d_out;

    const size_t BND = (size_t)BB * NN * DD;
    float* ws  = (float*)d_ws;
    float* hi  = ws;            // B*N*D
    float* hjb = ws + BND;      // B*N*D
    float* xw3 = ws + 2 * BND;  // B*N*D

    k_proj<<<dim3(BB * NN / 8), dim3(512), 0, stream>>>(x, msg_w1, msg_b1,
                                                        upd_w1, upd_b1,
                                                        hi, hjb, xw3);
    k_fused<<<dim3(256), dim3(512), 0, stream>>>(adj, x, hi, hjb, xw3,
                                                 msg_w2, msg_b2,
                                                 upd_w1, upd_w2, upd_b2,
                                                 ln_g, ln_b, out);
}